// Round 4
// baseline (1321.905 us; speedup 1.0000x reference)
//
#include <hip/hip_runtime.h>

#define NN 100000
#define NE 1600000
#define D 32
#define CHUNK 64

// ---------------- bf16 helpers (manual, round-to-nearest-even) ----------------

__device__ inline unsigned short f2b(float f) {
  unsigned int u = __float_as_uint(f);
  u = (u + 0x7FFFu + ((u >> 16) & 1u)) >> 16;
  return (unsigned short)u;
}
__device__ inline float b2f(unsigned short s) {
  return __uint_as_float(((unsigned int)s) << 16);
}

// ============================ CSR build ============================

__global__ void k_deg(const int* __restrict__ dst, int* __restrict__ cnt) {
  int i = blockIdx.x * blockDim.x + threadIdx.x;
  int stride = gridDim.x * blockDim.x;
  for (int e = i; e < NE; e += stride) atomicAdd(&cnt[dst[e]], 1);
}

__global__ void k_invdeg(const int* __restrict__ cnt, float* __restrict__ inv) {
  int v = blockIdx.x * blockDim.x + threadIdx.x;
  if (v < NN) inv[v] = 1.0f / (float)max(cnt[v], 1);
}

__global__ __launch_bounds__(1024) void k_scanA(const int* __restrict__ cnt,
                                                int* __restrict__ rowptr,
                                                int* __restrict__ partial) {
  __shared__ int lds[1024];
  int t = threadIdx.x;
  int i = blockIdx.x * 1024 + t;
  int v = (i < NN) ? cnt[i] : 0;
  lds[t] = v;
  __syncthreads();
  for (int off = 1; off < 1024; off <<= 1) {
    int add = (t >= off) ? lds[t - off] : 0;
    __syncthreads();
    lds[t] += add;
    __syncthreads();
  }
  if (i < NN) rowptr[i] = lds[t] - v;
  if (t == 1023) partial[blockIdx.x] = lds[1023];
}

__global__ void k_scanB(int* __restrict__ partial, int nb) {
  int acc = 0;
  for (int b = 0; b < nb; b++) { int t = partial[b]; partial[b] = acc; acc += t; }
  partial[nb] = acc;
}

__global__ __launch_bounds__(1024) void k_scanC(int* __restrict__ rowptr,
                                                const int* __restrict__ partial) {
  int t = threadIdx.x;
  int i = blockIdx.x * 1024 + t;
  if (i < NN) rowptr[i] += partial[blockIdx.x];
  if (i == 0) rowptr[NN] = NE;
}

__global__ void k_fill(const int* __restrict__ src, const int* __restrict__ dst,
                       const int* __restrict__ rowptr, int* __restrict__ fill,
                       int* __restrict__ eidx, int* __restrict__ src_p,
                       int* __restrict__ dst_p) {
  int i = blockIdx.x * blockDim.x + threadIdx.x;
  int stride = gridDim.x * blockDim.x;
  for (int e = i; e < NE; e += stride) {
    int d = dst[e];
    int slot = atomicAdd(&fill[d], 1);
    int p = rowptr[d] + slot;
    eidx[p] = e;
    src_p[p] = src[e];
    dst_p[p] = d;
  }
}

// ============================ helpers ============================

template <int K4>
__device__ inline float dot_lds(const float* __restrict__ lv, const float* __restrict__ Wc) {
  float acc = 0.f;
  const float4* v4 = (const float4*)lv;
#pragma unroll
  for (int kk = 0; kk < K4; kk++) {
    float4 h = v4[kk];
    acc = fmaf(h.x, Wc[4 * kk + 0], acc);
    acc = fmaf(h.y, Wc[4 * kk + 1], acc);
    acc = fmaf(h.z, Wc[4 * kk + 2], acc);
    acc = fmaf(h.w, Wc[4 * kk + 3], acc);
  }
  return acc;
}

// ============ node encoder + Q0 projection (Q0 = h0 @ Wn[0:32]) ============

__global__ __launch_bounds__(256) void k_node_enc_fin(
    const float* __restrict__ x,
    const float* __restrict__ ws, const float* __restrict__ bs,
    const float* __restrict__ wh, const float* __restrict__ bh,
    const float* __restrict__ we, const float* __restrict__ be,
    const float* __restrict__ Wn,  // w_node_s, rows 0..31
    float* __restrict__ Q0) {
  __shared__ float hrow[8][D];
  int t = threadIdx.x, j = t & 31, g = t >> 5;
  float Ws = ws[j], Bs = bs[j], Bh = bh[j], Be = be[j];
  float Wh[D], We_[D], Wq[D];
#pragma unroll
  for (int k = 0; k < D; k++) {
    Wh[k] = wh[k * D + j];
    We_[k] = we[k * D + j];
    Wq[k] = Wn[k * D + j];
  }
  for (int v = blockIdx.x * 8 + g; v < NN; v += gridDim.x * 8) {
    float h = fmaxf(fmaf(x[v], Ws, Bs), 0.f);
#pragma unroll
    for (int L = 0; L < 2; L++) {
      hrow[g][j] = h;
      h = fmaxf(dot_lds<8>(hrow[g], Wh) + Bh, 0.f);
    }
    hrow[g][j] = h;
    h = fmaxf(dot_lds<8>(hrow[g], We_) + Be, 0.f);
    hrow[g][j] = h;
    Q0[(size_t)v * D + j] = dot_lds<8>(hrow[g], Wq);
  }
}

// ==== node finalize: h = acc/deg; project P2/Q and P3; zero acc ====

__global__ __launch_bounds__(256) void k_fin(
    float* __restrict__ acc, const float* __restrict__ inv_deg,
    const float* __restrict__ We,  // [96][32] NEXT edge layer (rows 32..95 used)
    const float* __restrict__ Wn,  // [64][32] NEXT node msg (rows 0..31 used)
    float2* __restrict__ R2, float* __restrict__ P3out) {
  __shared__ float hrow[8][D];
  int t = threadIdx.x, j = t & 31, g = t >> 5;
  float Wp2[D], Wp3[D], Wq[D];
#pragma unroll
  for (int k = 0; k < D; k++) {
    Wp2[k] = We[(32 + k) * D + j];
    Wp3[k] = We[(64 + k) * D + j];
    Wq[k] = Wn[k * D + j];
  }
  for (int v = blockIdx.x * 8 + g; v < NN; v += gridDim.x * 8) {
    float h = acc[(size_t)v * D + j] * inv_deg[v];
    acc[(size_t)v * D + j] = 0.f;
    hrow[g][j] = h;
    float p2 = dot_lds<8>(hrow[g], Wp2);
    float q = dot_lds<8>(hrow[g], Wq);
    float p3 = dot_lds<8>(hrow[g], Wp3);
    R2[(size_t)v * D + j] = make_float2(p2, q);
    P3out[(size_t)v * D + j] = p3;
  }
}

// ==== final node finalize: P2f/P3f [NN,3] for the 96x3 output layer ====

__global__ __launch_bounds__(256) void k_fin4(
    float* __restrict__ acc, const float* __restrict__ inv_deg,
    const float* __restrict__ We,  // w_edge_e [96][3]
    float* __restrict__ P2f, float* __restrict__ P3f) {
  __shared__ float hrow[8][D];
  int t = threadIdx.x, j = t & 31, g = t >> 5;
  for (int v = blockIdx.x * 8 + g; v < NN; v += gridDim.x * 8) {
    float h = acc[(size_t)v * D + j] * inv_deg[v];
    hrow[g][j] = h;
    if (j < 6) {
      int c = j % 3;
      int off = (j < 3) ? 32 : 64;
      float s = 0.f;
#pragma unroll
      for (int k = 0; k < D; k++) s = fmaf(hrow[g][k], We[(off + k) * 3 + c], s);
      if (j < 3) P2f[(size_t)v * 3 + c] = s;
      else       P3f[(size_t)v * 3 + c] = s;
    }
  }
}

// ==== fused: edge encoder + first message + segmented scatter (4-edge ILP) ====

__global__ __launch_bounds__(256) void k_fe0(
    const float* __restrict__ edge_attr, const int* __restrict__ eidx,
    const float* __restrict__ Q0,
    const int* __restrict__ src_p, const int* __restrict__ dst_p,
    float* __restrict__ acc,
    const float* __restrict__ ws, const float* __restrict__ bs,
    const float* __restrict__ wh, const float* __restrict__ bh,
    const float* __restrict__ we, const float* __restrict__ be,
    const float* __restrict__ Wn,  // w_node_s rows 32..63
    unsigned short* __restrict__ h_edge) {
  __shared__ float tile[8][4][D];
  int t = threadIdx.x, j = t & 31, g = t >> 5;
  float Ws0 = ws[0 * D + j], Ws1 = ws[1 * D + j], Ws2 = ws[2 * D + j];
  float Bs = bs[j], Bh = bh[j], Be = be[j];
  float Wh[D], We_[D], W2[D];
#pragma unroll
  for (int k = 0; k < D; k++) {
    Wh[k] = wh[k * D + j];
    We_[k] = we[k * D + j];
    W2[k] = Wn[(32 + k) * D + j];
  }
  int p0 = (blockIdx.x * 8 + g) * CHUNK;
  float accv = 0.f;
  int cur = dst_p[p0];
  for (int batch = 0; batch < CHUNK / 4; ++batch) {
    int pb = p0 + batch * 4;
    int s[4], d[4], e[4];
#pragma unroll
    for (int i = 0; i < 4; i++) {
      s[i] = src_p[pb + i];
      d[i] = dst_p[pb + i];
      e[i] = eidx[pb + i];
    }
    float ax[4], ay[4], az[4], q[4];
#pragma unroll
    for (int i = 0; i < 4; i++) {
      const float* ap = &edge_attr[(size_t)e[i] * 3];
      ax[i] = ap[0]; ay[i] = ap[1]; az[i] = ap[2];
      q[i] = Q0[(size_t)s[i] * D + j];
    }
    float h[4];
#pragma unroll
    for (int i = 0; i < 4; i++)
      h[i] = fmaxf(fmaf(ax[i], Ws0, fmaf(ay[i], Ws1, fmaf(az[i], Ws2, Bs))), 0.f);
#pragma unroll
    for (int L = 0; L < 2; L++) {
#pragma unroll
      for (int i = 0; i < 4; i++) tile[g][i][j] = h[i];
#pragma unroll
      for (int i = 0; i < 4; i++) h[i] = fmaxf(dot_lds<8>(tile[g][i], Wh) + Bh, 0.f);
    }
#pragma unroll
    for (int i = 0; i < 4; i++) tile[g][i][j] = h[i];
#pragma unroll
    for (int i = 0; i < 4; i++) h[i] = fmaxf(dot_lds<8>(tile[g][i], We_) + Be, 0.f);
#pragma unroll
    for (int i = 0; i < 4; i++) h_edge[(size_t)(pb + i) * D + j] = f2b(h[i]);
#pragma unroll
    for (int i = 0; i < 4; i++) tile[g][i][j] = h[i];
    float m[4];
#pragma unroll
    for (int i = 0; i < 4; i++) m[i] = fmaxf(dot_lds<8>(tile[g][i], W2) + q[i], 0.f);
#pragma unroll
    for (int i = 0; i < 4; i++) {
      if (d[i] != cur) {
        atomicAdd(&acc[(size_t)cur * D + j], accv);
        accv = 0.f;
        cur = d[i];
      }
      accv += m[i];
    }
  }
  atomicAdd(&acc[(size_t)cur * D + j], accv);
}

// ==== fused: edge update + next message + segmented scatter (4-edge ILP) ====
// h_new = relu(h_e@We[0:32] + P2[s] + P3[d] + b); msg = relu(h_new@Wn[32:64] + Q[s])

__global__ __launch_bounds__(256) void k_fe(
    unsigned short* __restrict__ h_edge, const float2* __restrict__ R2,
    const float* __restrict__ P3, const int* __restrict__ src_p,
    const int* __restrict__ dst_p, float* __restrict__ acc,
    const float* __restrict__ We, const float* __restrict__ be,
    const float* __restrict__ Wn) {
  __shared__ float tile[8][4][D];
  int t = threadIdx.x, j = t & 31, g = t >> 5;
  float W1[D], W2[D];
#pragma unroll
  for (int k = 0; k < D; k++) {
    W1[k] = We[k * D + j];
    W2[k] = Wn[(32 + k) * D + j];
  }
  float B = be[j];
  int p0 = (blockIdx.x * 8 + g) * CHUNK;
  float accv = 0.f;
  int cur = dst_p[p0];
  // prefetch first 4 rows (4 rows x 32ch x bf16 = 256B = 32 lanes x uint2)
  uint2 gh = ((const uint2*)(h_edge + (size_t)p0 * D))[j];
  for (int batch = 0; batch < CHUNK / 4; ++batch) {
    int pb = p0 + batch * 4;
    float4 tv;
    tv.x = b2f((unsigned short)(gh.x & 0xFFFFu));
    tv.y = b2f((unsigned short)(gh.x >> 16));
    tv.z = b2f((unsigned short)(gh.y & 0xFFFFu));
    tv.w = b2f((unsigned short)(gh.y >> 16));
    ((float4*)tile[g])[j] = tv;
    int s[4], d[4];
    float2 r[4];
    float p3v[4];
#pragma unroll
    for (int i = 0; i < 4; i++) {
      s[i] = src_p[pb + i];
      d[i] = dst_p[pb + i];
    }
#pragma unroll
    for (int i = 0; i < 4; i++) {
      r[i] = R2[(size_t)s[i] * D + j];
      p3v[i] = P3[(size_t)d[i] * D + j];
    }
    if (batch < CHUNK / 4 - 1)
      gh = ((const uint2*)(h_edge + (size_t)(pb + 4) * D))[j];
    // 4 independent edge-update dots
    float hn[4];
#pragma unroll
    for (int i = 0; i < 4; i++) {
      hn[i] = fmaxf(B + r[i].x + p3v[i] + dot_lds<8>(tile[g][i], W1), 0.f);
      h_edge[(size_t)(pb + i) * D + j] = f2b(hn[i]);
    }
    // 4 independent message dots
#pragma unroll
    for (int i = 0; i < 4; i++) tile[g][i][j] = hn[i];
    float m[4];
#pragma unroll
    for (int i = 0; i < 4; i++) m[i] = fmaxf(dot_lds<8>(tile[g][i], W2) + r[i].y, 0.f);
#pragma unroll
    for (int i = 0; i < 4; i++) {
      if (d[i] != cur) {
        atomicAdd(&acc[(size_t)cur * D + j], accv);
        accv = 0.f;
        cur = d[i];
      }
      accv += m[i];
    }
  }
  atomicAdd(&acc[(size_t)cur * D + j], accv);
}

// ==== final edge layer: out[eidx[p]] = ea + h_e@We[0:32] + P2f[s] + P3f[d] + b ====

__global__ __launch_bounds__(256) void k_fe4(
    const unsigned short* __restrict__ h_edge, const float* __restrict__ edge_attr,
    const int* __restrict__ eidx, const int* __restrict__ src_p,
    const int* __restrict__ dst_p, const float* __restrict__ P2f,
    const float* __restrict__ P3f, const float* __restrict__ We,  // [96][3]
    const float* __restrict__ be, float* __restrict__ out) {
  int t = threadIdx.x, j = t & 31, g = t >> 5;
  float Wc0 = We[j * 3 + 0], Wc1 = We[j * 3 + 1], Wc2 = We[j * 3 + 2];
  float B0 = be[0], B1 = be[1], B2 = be[2];
  int ngroups = gridDim.x * 8;
  for (int p = blockIdx.x * 8 + g; p < NE; p += ngroups) {
    float h = b2f(h_edge[(size_t)p * D + j]);
    int s = src_p[p], d = dst_p[p], e = eidx[p];
    float c0 = h * Wc0, c1 = h * Wc1, c2 = h * Wc2;
#pragma unroll
    for (int off = 16; off; off >>= 1) {
      c0 += __shfl_xor(c0, off, 32);
      c1 += __shfl_xor(c1, off, 32);
      c2 += __shfl_xor(c2, off, 32);
    }
    if (j == 0) {
      out[(size_t)e * 3 + 0] = edge_attr[(size_t)e * 3 + 0] + P2f[(size_t)s * 3 + 0] + P3f[(size_t)d * 3 + 0] + B0 + c0;
      out[(size_t)e * 3 + 1] = edge_attr[(size_t)e * 3 + 1] + P2f[(size_t)s * 3 + 1] + P3f[(size_t)d * 3 + 1] + B1 + c1;
      out[(size_t)e * 3 + 2] = edge_attr[(size_t)e * 3 + 2] + P2f[(size_t)s * 3 + 2] + P3f[(size_t)d * 3 + 2] + B2 + c2;
    }
  }
}

// ============================ launch ============================

extern "C" void kernel_launch(void* const* d_in, const int* in_sizes, int n_in,
                              void* d_out, int out_size, void* d_ws, size_t ws_size,
                              hipStream_t stream) {
  const float* x = (const float*)d_in[0];
  const float* edge_attr = (const float*)d_in[1];
  const int* ei = (const int*)d_in[2];
  const int* src = ei;
  const int* dst = ei + NE;
  const float* w_enc_node_s = (const float*)d_in[3];
  const float* b_enc_node_s = (const float*)d_in[4];
  const float* w_enc_node_h = (const float*)d_in[5];
  const float* b_enc_node_h = (const float*)d_in[6];
  const float* w_enc_node_e = (const float*)d_in[7];
  const float* b_enc_node_e = (const float*)d_in[8];
  const float* w_enc_edge_s = (const float*)d_in[9];
  const float* b_enc_edge_s = (const float*)d_in[10];
  const float* w_enc_edge_h = (const float*)d_in[11];
  const float* b_enc_edge_h = (const float*)d_in[12];
  const float* w_enc_edge_e = (const float*)d_in[13];
  const float* b_enc_edge_e = (const float*)d_in[14];
  const float* w_node_s = (const float*)d_in[15];
  const float* w_node_h = (const float*)d_in[16];
  const float* w_node_e = (const float*)d_in[17];
  const float* w_edge_s = (const float*)d_in[18];
  const float* b_edge_s = (const float*)d_in[19];
  const float* w_edge_h = (const float*)d_in[20];
  const float* b_edge_h = (const float*)d_in[21];
  const float* w_edge_e = (const float*)d_in[22];
  const float* b_edge_e = (const float*)d_in[23];

  // workspace layout (~187 MB total; round-1's 238 MB was proven safe)
  char* w = (char*)d_ws;
  unsigned short* h_edge = (unsigned short*)w; w += (size_t)NE * D * 2;  // 102.4 MB
  int* eidx = (int*)w;        w += (size_t)NE * 4;            // 6.4 MB
  int* src_p = (int*)w;       w += (size_t)NE * 4;            // 6.4 MB
  int* dst_p = (int*)w;       w += (size_t)NE * 4;            // 6.4 MB
  float* acc = (float*)w;     w += (size_t)NN * D * 4;        // 12.8 MB
  float2* R2 = (float2*)w;    w += (size_t)NN * D * 8;        // 25.6 MB
  float* P3 = (float*)w;      w += (size_t)NN * D * 4;        // 12.8 MB (aliased by P2f/P3f later)
  float* Q0 = (float*)w;      w += (size_t)NN * D * 4;        // 12.8 MB
  float* P2f = P3;
  float* P3f = P3 + (size_t)NN * 3;
  int* cnt = (int*)w;         w += (size_t)NN * 4;
  float* inv_deg = (float*)w; w += (size_t)NN * 4;
  int* rowptr = (int*)w;      w += (size_t)(NN + 1) * 4;
  int* fill = (int*)w;        w += (size_t)NN * 4;
  int* partial = (int*)w;     w += 4096;

  hipMemsetAsync(cnt, 0, (size_t)NN * 4, stream);
  hipMemsetAsync(fill, 0, (size_t)NN * 4, stream);
  hipMemsetAsync(acc, 0, (size_t)NN * D * 4, stream);

  k_deg<<<1024, 256, 0, stream>>>(dst, cnt);
  k_invdeg<<<(NN + 255) / 256, 256, 0, stream>>>(cnt, inv_deg);
  int nb = (NN + 1023) / 1024;
  k_scanA<<<nb, 1024, 0, stream>>>(cnt, rowptr, partial);
  k_scanB<<<1, 1, 0, stream>>>(partial, nb);
  k_scanC<<<nb, 1024, 0, stream>>>(rowptr, partial);
  k_fill<<<1024, 256, 0, stream>>>(src, dst, rowptr, fill, eidx, src_p, dst_p);

  // node encoder -> Q0
  k_node_enc_fin<<<1024, 256, 0, stream>>>(x, w_enc_node_s, b_enc_node_s,
                                           w_enc_node_h, b_enc_node_h,
                                           w_enc_node_e, b_enc_node_e,
                                           w_node_s, Q0);

  int feb = NE / CHUNK / 8;  // 3125 blocks

  // edge encoder + msg(A_s) -> acc
  k_fe0<<<feb, 256, 0, stream>>>(edge_attr, eidx, Q0, src_p, dst_p, acc,
                                 w_enc_edge_s, b_enc_edge_s,
                                 w_enc_edge_h, b_enc_edge_h,
                                 w_enc_edge_e, b_enc_edge_e,
                                 w_node_s, h_edge);
  // h1 projections for B_s (w_edge_s) and msg A_h1 (w_node_h)
  k_fin<<<1024, 256, 0, stream>>>(acc, inv_deg, w_edge_s, w_node_h, R2, P3);
  // B_s + msg(A_h1)
  k_fe<<<feb, 256, 0, stream>>>(h_edge, R2, P3, src_p, dst_p, acc,
                                w_edge_s, b_edge_s, w_node_h);
  // h2 projections for B_h1 (w_edge_h) and msg A_h2 (w_node_h)
  k_fin<<<1024, 256, 0, stream>>>(acc, inv_deg, w_edge_h, w_node_h, R2, P3);
  // B_h1 + msg(A_h2)
  k_fe<<<feb, 256, 0, stream>>>(h_edge, R2, P3, src_p, dst_p, acc,
                                w_edge_h, b_edge_h, w_node_h);
  // h3 projections for B_h2 (w_edge_h) and msg A_e (w_node_e)
  k_fin<<<1024, 256, 0, stream>>>(acc, inv_deg, w_edge_h, w_node_e, R2, P3);
  // B_h2 + msg(A_e)
  k_fe<<<feb, 256, 0, stream>>>(h_edge, R2, P3, src_p, dst_p, acc,
                                w_edge_h, b_edge_h, w_node_e);
  // h4 -> P2f/P3f for final 96x3 layer
  k_fin4<<<1024, 256, 0, stream>>>(acc, inv_deg, w_edge_e, P2f, P3f);
  // final edge layer + residual, scatter to original order
  k_fe4<<<2048, 256, 0, stream>>>(h_edge, edge_attr, eidx, src_p, dst_p,
                                  P2f, P3f, w_edge_e, b_edge_e, (float*)d_out);
}

// Round 5
// 1067.768 us; speedup vs baseline: 1.2380x; 1.2380x over previous
//
#include <hip/hip_runtime.h>

#define NN 100000
#define NE 1600000
#define D 32

typedef short short8 __attribute__((ext_vector_type(8)));
typedef float f32x4 __attribute__((ext_vector_type(4)));

union ABfrag { int4 i; short8 s; };

// ---------------- bf16 helpers ----------------

__device__ inline unsigned short f2b(float f) {
  unsigned int u = __float_as_uint(f);
  u = (u + 0x7FFFu + ((u >> 16) & 1u)) >> 16;
  return (unsigned short)u;
}
__device__ inline float b2f(unsigned short s) {
  return __uint_as_float(((unsigned int)s) << 16);
}
__device__ inline unsigned cvt_pk_bf16(float lo, float hi) {
  unsigned r;
  asm("v_cvt_pk_bf16_f32 %0, %1, %2" : "=v"(r) : "v"(lo), "v"(hi));
  return r;
}
__device__ inline void splitw(float w, unsigned short& h, unsigned short& l) {
  h = f2b(w);
  l = f2b(w - b2f(h));
}

// ============================ CSR build ============================

__global__ void k_deg(const int* __restrict__ dst, int* __restrict__ cnt) {
  int i = blockIdx.x * blockDim.x + threadIdx.x;
  int stride = gridDim.x * blockDim.x;
  for (int e = i; e < NE; e += stride) atomicAdd(&cnt[dst[e]], 1);
}

__global__ void k_invdeg(const int* __restrict__ cnt, float* __restrict__ inv) {
  int v = blockIdx.x * blockDim.x + threadIdx.x;
  if (v < NN) inv[v] = 1.0f / (float)max(cnt[v], 1);
}

__global__ __launch_bounds__(1024) void k_scanA(const int* __restrict__ cnt,
                                                int* __restrict__ rowptr,
                                                int* __restrict__ partial) {
  __shared__ int lds[1024];
  int t = threadIdx.x;
  int i = blockIdx.x * 1024 + t;
  int v = (i < NN) ? cnt[i] : 0;
  lds[t] = v;
  __syncthreads();
  for (int off = 1; off < 1024; off <<= 1) {
    int add = (t >= off) ? lds[t - off] : 0;
    __syncthreads();
    lds[t] += add;
    __syncthreads();
  }
  if (i < NN) rowptr[i] = lds[t] - v;
  if (t == 1023) partial[blockIdx.x] = lds[1023];
}

__global__ void k_scanB(int* __restrict__ partial, int nb) {
  int acc = 0;
  for (int b = 0; b < nb; b++) { int t = partial[b]; partial[b] = acc; acc += t; }
  partial[nb] = acc;
}

__global__ __launch_bounds__(1024) void k_scanC(int* __restrict__ rowptr,
                                                const int* __restrict__ partial) {
  int t = threadIdx.x;
  int i = blockIdx.x * 1024 + t;
  if (i < NN) rowptr[i] += partial[blockIdx.x];
  if (i == 0) rowptr[NN] = NE;
}

__global__ void k_fill(const int* __restrict__ src, const int* __restrict__ dst,
                       const int* __restrict__ rowptr, int* __restrict__ fill,
                       int* __restrict__ eidx, int* __restrict__ src_p,
                       int* __restrict__ dst_p) {
  int i = blockIdx.x * blockDim.x + threadIdx.x;
  int stride = gridDim.x * blockDim.x;
  for (int e = i; e < NE; e += stride) {
    int d = dst[e];
    int slot = atomicAdd(&fill[d], 1);
    int p = rowptr[d] + slot;
    eidx[p] = e;
    src_p[p] = src[e];
    dst_p[p] = d;
  }
}

// ============================ VALU dot helper (node kernels) ============================

template <int K4>
__device__ inline float dot_lds(const float* __restrict__ lv, const float* __restrict__ Wc) {
  float acc = 0.f;
  const float4* v4 = (const float4*)lv;
#pragma unroll
  for (int kk = 0; kk < K4; kk++) {
    float4 h = v4[kk];
    acc = fmaf(h.x, Wc[4 * kk + 0], acc);
    acc = fmaf(h.y, Wc[4 * kk + 1], acc);
    acc = fmaf(h.z, Wc[4 * kk + 2], acc);
    acc = fmaf(h.w, Wc[4 * kk + 3], acc);
  }
  return acc;
}

// ============ node encoder + Q0 projection ============

__global__ __launch_bounds__(256) void k_node_enc_fin(
    const float* __restrict__ x,
    const float* __restrict__ ws, const float* __restrict__ bs,
    const float* __restrict__ wh, const float* __restrict__ bh,
    const float* __restrict__ we, const float* __restrict__ be,
    const float* __restrict__ Wn,  // w_node_s, rows 0..31
    float* __restrict__ Q0) {
  __shared__ float hrow[8][D];
  int t = threadIdx.x, j = t & 31, g = t >> 5;
  float Ws = ws[j], Bs = bs[j], Bh = bh[j], Be = be[j];
  float Wh[D], We_[D], Wq[D];
#pragma unroll
  for (int k = 0; k < D; k++) {
    Wh[k] = wh[k * D + j];
    We_[k] = we[k * D + j];
    Wq[k] = Wn[k * D + j];
  }
  for (int v = blockIdx.x * 8 + g; v < NN; v += gridDim.x * 8) {
    float h = fmaxf(fmaf(x[v], Ws, Bs), 0.f);
#pragma unroll
    for (int L = 0; L < 2; L++) {
      hrow[g][j] = h;
      h = fmaxf(dot_lds<8>(hrow[g], Wh) + Bh, 0.f);
    }
    hrow[g][j] = h;
    h = fmaxf(dot_lds<8>(hrow[g], We_) + Be, 0.f);
    hrow[g][j] = h;
    Q0[(size_t)v * D + j] = dot_lds<8>(hrow[g], Wq);
  }
}

// ==== node finalize: h = acc/deg; project P2/Q and P3; zero acc ====

__global__ __launch_bounds__(256) void k_fin(
    float* __restrict__ acc, const float* __restrict__ inv_deg,
    const float* __restrict__ We,  // [96][32] NEXT edge layer (rows 32..95 used)
    const float* __restrict__ Wn,  // [64][32] NEXT node msg (rows 0..31 used)
    float2* __restrict__ R2, float* __restrict__ P3out) {
  __shared__ float hrow[8][D];
  int t = threadIdx.x, j = t & 31, g = t >> 5;
  float Wp2[D], Wp3[D], Wq[D];
#pragma unroll
  for (int k = 0; k < D; k++) {
    Wp2[k] = We[(32 + k) * D + j];
    Wp3[k] = We[(64 + k) * D + j];
    Wq[k] = Wn[k * D + j];
  }
  for (int v = blockIdx.x * 8 + g; v < NN; v += gridDim.x * 8) {
    float h = acc[(size_t)v * D + j] * inv_deg[v];
    acc[(size_t)v * D + j] = 0.f;
    hrow[g][j] = h;
    float p2 = dot_lds<8>(hrow[g], Wp2);
    float q = dot_lds<8>(hrow[g], Wq);
    float p3 = dot_lds<8>(hrow[g], Wp3);
    R2[(size_t)v * D + j] = make_float2(p2, q);
    P3out[(size_t)v * D + j] = p3;
  }
}

// ==== final node finalize: P2f/P3f [NN,3] ====

__global__ __launch_bounds__(256) void k_fin4(
    float* __restrict__ acc, const float* __restrict__ inv_deg,
    const float* __restrict__ We,  // w_edge_e [96][3]
    float* __restrict__ P2f, float* __restrict__ P3f) {
  __shared__ float hrow[8][D];
  int t = threadIdx.x, j = t & 31, g = t >> 5;
  for (int v = blockIdx.x * 8 + g; v < NN; v += gridDim.x * 8) {
    float h = acc[(size_t)v * D + j] * inv_deg[v];
    hrow[g][j] = h;
    if (j < 6) {
      int c = j % 3;
      int off = (j < 3) ? 32 : 64;
      float s = 0.f;
#pragma unroll
      for (int k = 0; k < D; k++) s = fmaf(hrow[g][k], We[(off + k) * 3 + c], s);
      if (j < 3) P2f[(size_t)v * 3 + c] = s;
      else       P3f[(size_t)v * 3 + c] = s;
    }
  }
}

// ============================ MFMA epilogue/transpose helpers ============================
// D layout (mfma_f32_16x16x32_bf16, verified m89): col = lane&15, row = (lane>>4)*4 + reg
// A layout: row = lane&15, k = (lane>>4)*8 + i ;  B layout: col = lane&15, k = (lane>>4)*8 + i

__device__ inline void ep_xpose_write(float* __restrict__ xw, f32x4 da, f32x4 db,
                                      float ba, float bb, int cl, int ch) {
#pragma unroll
  for (int r = 0; r < 4; r++) {
    xw[(cl * 4 + r) * 36 + ch] = fmaxf(da[r] + ba, 0.f);
    xw[(cl * 4 + r) * 36 + ch + 16] = fmaxf(db[r] + bb, 0.f);
  }
}

__device__ inline ABfrag xpose_read(const float* __restrict__ xw, int lane) {
  const float4* p = (const float4*)(xw + (lane & 15) * 36 + (lane >> 4) * 8);
  float4 v0 = p[0], v1 = p[1];
  ABfrag A;
  A.i = make_int4(cvt_pk_bf16(v0.x, v0.y), cvt_pk_bf16(v0.z, v0.w),
                  cvt_pk_bf16(v1.x, v1.y), cvt_pk_bf16(v1.z, v1.w));
  return A;
}

// ==== MFMA fused: edge encoder + first message + scatter ====

__global__ __launch_bounds__(256) void k_fe0_m(
    const float* __restrict__ edge_attr, const int* __restrict__ eidx,
    const float* __restrict__ Q0,
    const int* __restrict__ src_p, const int* __restrict__ dst_p,
    float* __restrict__ acc,
    const float* __restrict__ ws, const float* __restrict__ bs,
    const float* __restrict__ wh, const float* __restrict__ bh,
    const float* __restrict__ we, const float* __restrict__ be,
    const float* __restrict__ Wn,  // w_node_s rows 32..63
    unsigned short* __restrict__ h_edge) {
  __shared__ float xp[4][16 * 36];
  int lane = threadIdx.x & 63, wid = threadIdx.x >> 6;
  int cl = lane >> 4, ch = lane & 15;
  // layer-1 weights for this lane's 8 k-channels
  float wsv[3][8], bsv[8];
#pragma unroll
  for (int kk = 0; kk < 8; kk++) {
    int c = cl * 8 + kk;
    wsv[0][kk] = ws[c]; wsv[1][kk] = ws[32 + c]; wsv[2][kk] = ws[64 + c];
    bsv[kk] = bs[c];
  }
  ABfrag wha, whb, wea, web, w2ah, w2al, w2bh, w2bl;
#pragma unroll
  for (int kk = 0; kk < 8; kk++) {
    int k = cl * 8 + kk;
    wha.s[kk] = (short)f2b(wh[k * 32 + ch]);
    whb.s[kk] = (short)f2b(wh[k * 32 + ch + 16]);
    wea.s[kk] = (short)f2b(we[k * 32 + ch]);
    web.s[kk] = (short)f2b(we[k * 32 + ch + 16]);
    unsigned short hi_, lo_;
    splitw(Wn[(32 + k) * 32 + ch], hi_, lo_);      w2ah.s[kk] = (short)hi_; w2al.s[kk] = (short)lo_;
    splitw(Wn[(32 + k) * 32 + ch + 16], hi_, lo_); w2bh.s[kk] = (short)hi_; w2bl.s[kk] = (short)lo_;
  }
  float bha = bh[ch], bhb = bh[ch + 16], bea = be[ch], beb = be[ch + 16];
  int p0 = (blockIdx.x * 4 + wid) * 64;
  f32x4 z = {0.f, 0.f, 0.f, 0.f};
  for (int t = 0; t < 4; t++) {
    int pb = p0 + t * 16;
    // layer 1 (3 -> 32), computed directly in A-frag layout
    int e = eidx[pb + (lane & 15)];
    float a0 = edge_attr[(size_t)e * 3], a1 = edge_attr[(size_t)e * 3 + 1],
          a2 = edge_attr[(size_t)e * 3 + 2];
    float h1[8];
#pragma unroll
    for (int kk = 0; kk < 8; kk++)
      h1[kk] = fmaxf(fmaf(a0, wsv[0][kk], fmaf(a1, wsv[1][kk], fmaf(a2, wsv[2][kk], bsv[kk]))), 0.f);
    ABfrag A;
    A.i = make_int4(cvt_pk_bf16(h1[0], h1[1]), cvt_pk_bf16(h1[2], h1[3]),
                    cvt_pk_bf16(h1[4], h1[5]), cvt_pk_bf16(h1[6], h1[7]));
    // layer 2 (wh)
    f32x4 da = __builtin_amdgcn_mfma_f32_16x16x32_bf16(A.s, wha.s, z, 0, 0, 0);
    f32x4 db = __builtin_amdgcn_mfma_f32_16x16x32_bf16(A.s, whb.s, z, 0, 0, 0);
    ep_xpose_write(xp[wid], da, db, bha, bhb, cl, ch);
    A = xpose_read(xp[wid], lane);
    // layer 3 (wh)
    da = __builtin_amdgcn_mfma_f32_16x16x32_bf16(A.s, wha.s, z, 0, 0, 0);
    db = __builtin_amdgcn_mfma_f32_16x16x32_bf16(A.s, whb.s, z, 0, 0, 0);
    ep_xpose_write(xp[wid], da, db, bha, bhb, cl, ch);
    A = xpose_read(xp[wid], lane);
    // layer 4 (we) -> h_edge store + transpose
    da = __builtin_amdgcn_mfma_f32_16x16x32_bf16(A.s, wea.s, z, 0, 0, 0);
    db = __builtin_amdgcn_mfma_f32_16x16x32_bf16(A.s, web.s, z, 0, 0, 0);
#pragma unroll
    for (int r = 0; r < 4; r++) {
      float h0 = fmaxf(da[r] + bea, 0.f);
      float h1v = fmaxf(db[r] + beb, 0.f);
      int p = pb + cl * 4 + r;
      h_edge[(size_t)p * 32 + ch] = f2b(h0);
      h_edge[(size_t)p * 32 + ch + 16] = f2b(h1v);
      xp[wid][(cl * 4 + r) * 36 + ch] = h0;
      xp[wid][(cl * 4 + r) * 36 + ch + 16] = h1v;
    }
    A = xpose_read(xp[wid], lane);
    // message (w2, hi/lo split)
    f32x4 ma = __builtin_amdgcn_mfma_f32_16x16x32_bf16(A.s, w2al.s, z, 0, 0, 0);
    ma = __builtin_amdgcn_mfma_f32_16x16x32_bf16(A.s, w2ah.s, ma, 0, 0, 0);
    f32x4 mb = __builtin_amdgcn_mfma_f32_16x16x32_bf16(A.s, w2bl.s, z, 0, 0, 0);
    mb = __builtin_amdgcn_mfma_f32_16x16x32_bf16(A.s, w2bh.s, mb, 0, 0, 0);
    // q gathers + in-lane merged atomic scatter (dst_p sorted, non-decreasing)
    int4 sv = *(const int4*)(src_p + pb + cl * 4);
    int4 dv = *(const int4*)(dst_p + pb + cl * 4);
    int sa[4] = {sv.x, sv.y, sv.z, sv.w};
    int dda[4] = {dv.x, dv.y, dv.z, dv.w};
    float va = 0.f, vb = 0.f;
    int cur = dda[0];
#pragma unroll
    for (int r = 0; r < 4; r++) {
      float q0 = Q0[(size_t)sa[r] * 32 + ch];
      float q1 = Q0[(size_t)sa[r] * 32 + ch + 16];
      float xa = fmaxf(ma[r] + q0, 0.f);
      float xb = fmaxf(mb[r] + q1, 0.f);
      if (dda[r] != cur) {
        atomicAdd(&acc[(size_t)cur * 32 + ch], va);
        atomicAdd(&acc[(size_t)cur * 32 + ch + 16], vb);
        va = 0.f; vb = 0.f; cur = dda[r];
      }
      va += xa; vb += xb;
    }
    atomicAdd(&acc[(size_t)cur * 32 + ch], va);
    atomicAdd(&acc[(size_t)cur * 32 + ch + 16], vb);
  }
}

// ==== MFMA fused: edge update + message + scatter ====
// h_new = relu(h_e@We[0:32] + P2[s] + P3[d] + b); msg = relu(h_new@Wn[32:64] + Q[s])

__global__ __launch_bounds__(256) void k_fe_m(
    unsigned short* __restrict__ h_edge, const float2* __restrict__ R2,
    const float* __restrict__ P3, const int* __restrict__ src_p,
    const int* __restrict__ dst_p, float* __restrict__ acc,
    const float* __restrict__ We, const float* __restrict__ be,
    const float* __restrict__ Wn) {
  __shared__ float xp[4][16 * 36];
  int lane = threadIdx.x & 63, wid = threadIdx.x >> 6;
  int cl = lane >> 4, ch = lane & 15;
  ABfrag b1ah, b1al, b1bh, b1bl, b2ah, b2al, b2bh, b2bl;
#pragma unroll
  for (int kk = 0; kk < 8; kk++) {
    int k = cl * 8 + kk;
    unsigned short hi_, lo_;
    splitw(We[k * 32 + ch], hi_, lo_);             b1ah.s[kk] = (short)hi_; b1al.s[kk] = (short)lo_;
    splitw(We[k * 32 + ch + 16], hi_, lo_);        b1bh.s[kk] = (short)hi_; b1bl.s[kk] = (short)lo_;
    splitw(Wn[(32 + k) * 32 + ch], hi_, lo_);      b2ah.s[kk] = (short)hi_; b2al.s[kk] = (short)lo_;
    splitw(Wn[(32 + k) * 32 + ch + 16], hi_, lo_); b2bh.s[kk] = (short)hi_; b2bl.s[kk] = (short)lo_;
  }
  float bea = be[ch], beb = be[ch + 16];
  int p0 = (blockIdx.x * 4 + wid) * 64;
  f32x4 z = {0.f, 0.f, 0.f, 0.f};
  for (int t = 0; t < 4; t++) {
    int pb = p0 + t * 16;
    ABfrag A;
    A.i = *(const int4*)(h_edge + (size_t)(pb + (lane & 15)) * 32 + cl * 8);
    f32x4 da = __builtin_amdgcn_mfma_f32_16x16x32_bf16(A.s, b1al.s, z, 0, 0, 0);
    da = __builtin_amdgcn_mfma_f32_16x16x32_bf16(A.s, b1ah.s, da, 0, 0, 0);
    f32x4 db = __builtin_amdgcn_mfma_f32_16x16x32_bf16(A.s, b1bl.s, z, 0, 0, 0);
    db = __builtin_amdgcn_mfma_f32_16x16x32_bf16(A.s, b1bh.s, db, 0, 0, 0);
    int4 sv = *(const int4*)(src_p + pb + cl * 4);
    int4 dv = *(const int4*)(dst_p + pb + cl * 4);
    int sa[4] = {sv.x, sv.y, sv.z, sv.w};
    int dda[4] = {dv.x, dv.y, dv.z, dv.w};
    float qa[4], qb[4];
#pragma unroll
    for (int r = 0; r < 4; r++) {
      float2 r0 = R2[(size_t)sa[r] * 32 + ch];
      float2 r1 = R2[(size_t)sa[r] * 32 + ch + 16];
      float p30 = P3[(size_t)dda[r] * 32 + ch];
      float p31 = P3[(size_t)dda[r] * 32 + ch + 16];
      qa[r] = r0.y; qb[r] = r1.y;
      float h0 = fmaxf(da[r] + r0.x + p30 + bea, 0.f);
      float h1v = fmaxf(db[r] + r1.x + p31 + beb, 0.f);
      int p = pb + cl * 4 + r;
      h_edge[(size_t)p * 32 + ch] = f2b(h0);
      h_edge[(size_t)p * 32 + ch + 16] = f2b(h1v);
      xp[wid][(cl * 4 + r) * 36 + ch] = h0;
      xp[wid][(cl * 4 + r) * 36 + ch + 16] = h1v;
    }
    ABfrag A2 = xpose_read(xp[wid], lane);
    f32x4 ma = __builtin_amdgcn_mfma_f32_16x16x32_bf16(A2.s, b2al.s, z, 0, 0, 0);
    ma = __builtin_amdgcn_mfma_f32_16x16x32_bf16(A2.s, b2ah.s, ma, 0, 0, 0);
    f32x4 mb = __builtin_amdgcn_mfma_f32_16x16x32_bf16(A2.s, b2bl.s, z, 0, 0, 0);
    mb = __builtin_amdgcn_mfma_f32_16x16x32_bf16(A2.s, b2bh.s, mb, 0, 0, 0);
    float va = 0.f, vb = 0.f;
    int cur = dda[0];
#pragma unroll
    for (int r = 0; r < 4; r++) {
      float xa = fmaxf(ma[r] + qa[r], 0.f);
      float xb = fmaxf(mb[r] + qb[r], 0.f);
      if (dda[r] != cur) {
        atomicAdd(&acc[(size_t)cur * 32 + ch], va);
        atomicAdd(&acc[(size_t)cur * 32 + ch + 16], vb);
        va = 0.f; vb = 0.f; cur = dda[r];
      }
      va += xa; vb += xb;
    }
    atomicAdd(&acc[(size_t)cur * 32 + ch], va);
    atomicAdd(&acc[(size_t)cur * 32 + ch + 16], vb);
  }
}

// ==== final edge layer: out[eidx[p]] = ea + h_e@We[0:32] + P2f[s] + P3f[d] + b ====

__global__ __launch_bounds__(256) void k_fe4(
    const unsigned short* __restrict__ h_edge, const float* __restrict__ edge_attr,
    const int* __restrict__ eidx, const int* __restrict__ src_p,
    const int* __restrict__ dst_p, const float* __restrict__ P2f,
    const float* __restrict__ P3f, const float* __restrict__ We,  // [96][3]
    const float* __restrict__ be, float* __restrict__ out) {
  int t = threadIdx.x, j = t & 31, g = t >> 5;
  float Wc0 = We[j * 3 + 0], Wc1 = We[j * 3 + 1], Wc2 = We[j * 3 + 2];
  float B0 = be[0], B1 = be[1], B2 = be[2];
  int ngroups = gridDim.x * 8;
  for (int p = blockIdx.x * 8 + g; p < NE; p += ngroups) {
    float h = b2f(h_edge[(size_t)p * D + j]);
    int s = src_p[p], d = dst_p[p], e = eidx[p];
    float c0 = h * Wc0, c1 = h * Wc1, c2 = h * Wc2;
#pragma unroll
    for (int off = 16; off; off >>= 1) {
      c0 += __shfl_xor(c0, off, 32);
      c1 += __shfl_xor(c1, off, 32);
      c2 += __shfl_xor(c2, off, 32);
    }
    if (j == 0) {
      out[(size_t)e * 3 + 0] = edge_attr[(size_t)e * 3 + 0] + P2f[(size_t)s * 3 + 0] + P3f[(size_t)d * 3 + 0] + B0 + c0;
      out[(size_t)e * 3 + 1] = edge_attr[(size_t)e * 3 + 1] + P2f[(size_t)s * 3 + 1] + P3f[(size_t)d * 3 + 1] + B1 + c1;
      out[(size_t)e * 3 + 2] = edge_attr[(size_t)e * 3 + 2] + P2f[(size_t)s * 3 + 2] + P3f[(size_t)d * 3 + 2] + B2 + c2;
    }
  }
}

// ============================ launch ============================

extern "C" void kernel_launch(void* const* d_in, const int* in_sizes, int n_in,
                              void* d_out, int out_size, void* d_ws, size_t ws_size,
                              hipStream_t stream) {
  const float* x = (const float*)d_in[0];
  const float* edge_attr = (const float*)d_in[1];
  const int* ei = (const int*)d_in[2];
  const int* src = ei;
  const int* dst = ei + NE;
  const float* w_enc_node_s = (const float*)d_in[3];
  const float* b_enc_node_s = (const float*)d_in[4];
  const float* w_enc_node_h = (const float*)d_in[5];
  const float* b_enc_node_h = (const float*)d_in[6];
  const float* w_enc_node_e = (const float*)d_in[7];
  const float* b_enc_node_e = (const float*)d_in[8];
  const float* w_enc_edge_s = (const float*)d_in[9];
  const float* b_enc_edge_s = (const float*)d_in[10];
  const float* w_enc_edge_h = (const float*)d_in[11];
  const float* b_enc_edge_h = (const float*)d_in[12];
  const float* w_enc_edge_e = (const float*)d_in[13];
  const float* b_enc_edge_e = (const float*)d_in[14];
  const float* w_node_s = (const float*)d_in[15];
  const float* w_node_h = (const float*)d_in[16];
  const float* w_node_e = (const float*)d_in[17];
  const float* w_edge_s = (const float*)d_in[18];
  const float* b_edge_s = (const float*)d_in[19];
  const float* w_edge_h = (const float*)d_in[20];
  const float* b_edge_h = (const float*)d_in[21];
  const float* w_edge_e = (const float*)d_in[22];
  const float* b_edge_e = (const float*)d_in[23];

  // workspace layout (~187 MB; 238 MB proven safe in round 1)
  char* w = (char*)d_ws;
  unsigned short* h_edge = (unsigned short*)w; w += (size_t)NE * D * 2;  // 102.4 MB
  int* eidx = (int*)w;        w += (size_t)NE * 4;
  int* src_p = (int*)w;       w += (size_t)NE * 4;
  int* dst_p = (int*)w;       w += (size_t)NE * 4;
  float* acc = (float*)w;     w += (size_t)NN * D * 4;
  float2* R2 = (float2*)w;    w += (size_t)NN * D * 8;
  float* P3 = (float*)w;      w += (size_t)NN * D * 4;
  float* Q0 = (float*)w;      w += (size_t)NN * D * 4;
  float* P2f = P3;
  float* P3f = P3 + (size_t)NN * 3;
  int* cnt = (int*)w;         w += (size_t)NN * 4;
  float* inv_deg = (float*)w; w += (size_t)NN * 4;
  int* rowptr = (int*)w;      w += (size_t)(NN + 1) * 4;
  int* fill = (int*)w;        w += (size_t)NN * 4;
  int* partial = (int*)w;     w += 4096;

  hipMemsetAsync(cnt, 0, (size_t)NN * 4, stream);
  hipMemsetAsync(fill, 0, (size_t)NN * 4, stream);
  hipMemsetAsync(acc, 0, (size_t)NN * D * 4, stream);

  k_deg<<<1024, 256, 0, stream>>>(dst, cnt);
  k_invdeg<<<(NN + 255) / 256, 256, 0, stream>>>(cnt, inv_deg);
  int nb = (NN + 1023) / 1024;
  k_scanA<<<nb, 1024, 0, stream>>>(cnt, rowptr, partial);
  k_scanB<<<1, 1, 0, stream>>>(partial, nb);
  k_scanC<<<nb, 1024, 0, stream>>>(rowptr, partial);
  k_fill<<<1024, 256, 0, stream>>>(src, dst, rowptr, fill, eidx, src_p, dst_p);

  k_node_enc_fin<<<1024, 256, 0, stream>>>(x, w_enc_node_s, b_enc_node_s,
                                           w_enc_node_h, b_enc_node_h,
                                           w_enc_node_e, b_enc_node_e,
                                           w_node_s, Q0);

  int feb = NE / 256;  // 6250 blocks: 4 waves x 64 edges

  k_fe0_m<<<feb, 256, 0, stream>>>(edge_attr, eidx, Q0, src_p, dst_p, acc,
                                   w_enc_edge_s, b_enc_edge_s,
                                   w_enc_edge_h, b_enc_edge_h,
                                   w_enc_edge_e, b_enc_edge_e,
                                   w_node_s, h_edge);
  k_fin<<<1024, 256, 0, stream>>>(acc, inv_deg, w_edge_s, w_node_h, R2, P3);
  k_fe_m<<<feb, 256, 0, stream>>>(h_edge, R2, P3, src_p, dst_p, acc,
                                  w_edge_s, b_edge_s, w_node_h);
  k_fin<<<1024, 256, 0, stream>>>(acc, inv_deg, w_edge_h, w_node_h, R2, P3);
  k_fe_m<<<feb, 256, 0, stream>>>(h_edge, R2, P3, src_p, dst_p, acc,
                                  w_edge_h, b_edge_h, w_node_h);
  k_fin<<<1024, 256, 0, stream>>>(acc, inv_deg, w_edge_h, w_node_e, R2, P3);
  k_fe_m<<<feb, 256, 0, stream>>>(h_edge, R2, P3, src_p, dst_p, acc,
                                  w_edge_h, b_edge_h, w_node_e);
  k_fin4<<<1024, 256, 0, stream>>>(acc, inv_deg, w_edge_e, P2f, P3f);
  k_fe4<<<2048, 256, 0, stream>>>(h_edge, edge_attr, eidx, src_p, dst_p,
                                  P2f, P3f, w_edge_e, b_edge_e, (float*)d_out);
}

// Round 6
// 943.810 us; speedup vs baseline: 1.4006x; 1.1313x over previous
//
#include <hip/hip_runtime.h>

#define NN 100000
#define NE 1600000
#define D 32

typedef short short8 __attribute__((ext_vector_type(8)));
typedef float f32x4 __attribute__((ext_vector_type(4)));

union ABfrag { int4 i; short8 s; };

// ---------------- bf16 helpers ----------------

__device__ inline unsigned short f2b(float f) {
  unsigned int u = __float_as_uint(f);
  u = (u + 0x7FFFu + ((u >> 16) & 1u)) >> 16;
  return (unsigned short)u;
}
__device__ inline float b2f(unsigned short s) {
  return __uint_as_float(((unsigned int)s) << 16);
}
__device__ inline unsigned cvt_pk_bf16(float lo, float hi) {
  unsigned r;
  asm("v_cvt_pk_bf16_f32 %0, %1, %2" : "=v"(r) : "v"(lo), "v"(hi));
  return r;
}
__device__ inline void splitw(float w, unsigned short& h, unsigned short& l) {
  h = f2b(w);
  l = f2b(w - b2f(h));
}

// ============================ CSR build ============================

__global__ void k_deg(const int* __restrict__ dst, int* __restrict__ cnt) {
  int i = blockIdx.x * blockDim.x + threadIdx.x;
  int stride = gridDim.x * blockDim.x;
  for (int e = i; e < NE; e += stride) atomicAdd(&cnt[dst[e]], 1);
}

__global__ void k_invdeg(const int* __restrict__ cnt, float* __restrict__ inv) {
  int v = blockIdx.x * blockDim.x + threadIdx.x;
  if (v < NN) inv[v] = 1.0f / (float)max(cnt[v], 1);
}

__global__ __launch_bounds__(1024) void k_scanA(const int* __restrict__ cnt,
                                                int* __restrict__ rowptr,
                                                int* __restrict__ partial) {
  __shared__ int lds[1024];
  int t = threadIdx.x;
  int i = blockIdx.x * 1024 + t;
  int v = (i < NN) ? cnt[i] : 0;
  lds[t] = v;
  __syncthreads();
  for (int off = 1; off < 1024; off <<= 1) {
    int add = (t >= off) ? lds[t - off] : 0;
    __syncthreads();
    lds[t] += add;
    __syncthreads();
  }
  if (i < NN) rowptr[i] = lds[t] - v;
  if (t == 1023) partial[blockIdx.x] = lds[1023];
}

__global__ __launch_bounds__(128) void k_scanB(int* __restrict__ partial, int nb) {
  __shared__ int s[128];
  int t = threadIdx.x;
  int v = (t < nb) ? partial[t] : 0;
  s[t] = v;
  __syncthreads();
  for (int off = 1; off < 128; off <<= 1) {
    int add = (t >= off) ? s[t - off] : 0;
    __syncthreads();
    s[t] += add;
    __syncthreads();
  }
  if (t < nb) partial[t] = s[t] - v;  // exclusive
}

__global__ __launch_bounds__(1024) void k_scanC(int* __restrict__ rowptr,
                                                const int* __restrict__ partial) {
  int t = threadIdx.x;
  int i = blockIdx.x * 1024 + t;
  if (i < NN) rowptr[i] += partial[blockIdx.x];
  if (i == 0) rowptr[NN] = NE;
}

__global__ void k_fill(const int* __restrict__ src, const int* __restrict__ dst,
                       const int* __restrict__ rowptr, int* __restrict__ fill,
                       int* __restrict__ eidx, int* __restrict__ src_p,
                       int* __restrict__ dst_p, int* __restrict__ inv_p) {
  int i = blockIdx.x * blockDim.x + threadIdx.x;
  int stride = gridDim.x * blockDim.x;
  for (int e = i; e < NE; e += stride) {
    int d = dst[e];
    int slot = atomicAdd(&fill[d], 1);
    int p = rowptr[d] + slot;
    eidx[p] = e;
    src_p[p] = src[e];
    dst_p[p] = d;
    inv_p[e] = p;
  }
}

// ============================ VALU dot helper (node kernels) ============================

template <int K4>
__device__ inline float dot_lds(const float* __restrict__ lv, const float* __restrict__ Wc) {
  float acc = 0.f;
  const float4* v4 = (const float4*)lv;
#pragma unroll
  for (int kk = 0; kk < K4; kk++) {
    float4 h = v4[kk];
    acc = fmaf(h.x, Wc[4 * kk + 0], acc);
    acc = fmaf(h.y, Wc[4 * kk + 1], acc);
    acc = fmaf(h.z, Wc[4 * kk + 2], acc);
    acc = fmaf(h.w, Wc[4 * kk + 3], acc);
  }
  return acc;
}

// ============ node encoder + Q0 projection ============

__global__ __launch_bounds__(256) void k_node_enc_fin(
    const float* __restrict__ x,
    const float* __restrict__ ws, const float* __restrict__ bs,
    const float* __restrict__ wh, const float* __restrict__ bh,
    const float* __restrict__ we, const float* __restrict__ be,
    const float* __restrict__ Wn,  // w_node_s, rows 0..31
    float* __restrict__ Q0) {
  __shared__ float hrow[8][D];
  int t = threadIdx.x, j = t & 31, g = t >> 5;
  float Ws = ws[j], Bs = bs[j], Bh = bh[j], Be = be[j];
  float Wh[D], We_[D], Wq[D];
#pragma unroll
  for (int k = 0; k < D; k++) {
    Wh[k] = wh[k * D + j];
    We_[k] = we[k * D + j];
    Wq[k] = Wn[k * D + j];
  }
  for (int v = blockIdx.x * 8 + g; v < NN; v += gridDim.x * 8) {
    float h = fmaxf(fmaf(x[v], Ws, Bs), 0.f);
#pragma unroll
    for (int L = 0; L < 2; L++) {
      hrow[g][j] = h;
      h = fmaxf(dot_lds<8>(hrow[g], Wh) + Bh, 0.f);
    }
    hrow[g][j] = h;
    h = fmaxf(dot_lds<8>(hrow[g], We_) + Be, 0.f);
    hrow[g][j] = h;
    Q0[(size_t)v * D + j] = dot_lds<8>(hrow[g], Wq);
  }
}

// ==== node finalize: h = acc/deg; project P2/Q and P3; zero acc ====

__global__ __launch_bounds__(256) void k_fin(
    float* __restrict__ acc, const float* __restrict__ inv_deg,
    const float* __restrict__ We,  // [96][32] NEXT edge layer (rows 32..95 used)
    const float* __restrict__ Wn,  // [64][32] NEXT node msg (rows 0..31 used)
    float2* __restrict__ R2, float* __restrict__ P3out) {
  __shared__ float hrow[8][D];
  int t = threadIdx.x, j = t & 31, g = t >> 5;
  float Wp2[D], Wp3[D], Wq[D];
#pragma unroll
  for (int k = 0; k < D; k++) {
    Wp2[k] = We[(32 + k) * D + j];
    Wp3[k] = We[(64 + k) * D + j];
    Wq[k] = Wn[k * D + j];
  }
  for (int v = blockIdx.x * 8 + g; v < NN; v += gridDim.x * 8) {
    float h = acc[(size_t)v * D + j] * inv_deg[v];
    acc[(size_t)v * D + j] = 0.f;
    hrow[g][j] = h;
    float p2 = dot_lds<8>(hrow[g], Wp2);
    float q = dot_lds<8>(hrow[g], Wq);
    float p3 = dot_lds<8>(hrow[g], Wp3);
    R2[(size_t)v * D + j] = make_float2(p2, q);
    P3out[(size_t)v * D + j] = p3;
  }
}

// ==== final node finalize: P2f/P3f [NN,3] ====

__global__ __launch_bounds__(256) void k_fin4(
    float* __restrict__ acc, const float* __restrict__ inv_deg,
    const float* __restrict__ We,  // w_edge_e [96][3]
    float* __restrict__ P2f, float* __restrict__ P3f) {
  __shared__ float hrow[8][D];
  int t = threadIdx.x, j = t & 31, g = t >> 5;
  for (int v = blockIdx.x * 8 + g; v < NN; v += gridDim.x * 8) {
    float h = acc[(size_t)v * D + j] * inv_deg[v];
    hrow[g][j] = h;
    if (j < 6) {
      int c = j % 3;
      int off = (j < 3) ? 32 : 64;
      float s = 0.f;
#pragma unroll
      for (int k = 0; k < D; k++) s = fmaf(hrow[g][k], We[(off + k) * 3 + c], s);
      if (j < 3) P2f[(size_t)v * 3 + c] = s;
      else       P3f[(size_t)v * 3 + c] = s;
    }
  }
}

// ============================ MFMA helpers ============================
// D layout (mfma_f32_16x16x32_bf16): col = lane&15, row = (lane>>4)*4 + reg
// A layout: row = lane&15, k = (lane>>4)*8 + i ;  B layout: col = lane&15, k = (lane>>4)*8 + i

__device__ inline void ep_xpose_write(float* __restrict__ xw, f32x4 da, f32x4 db,
                                      float ba, float bb, int cl, int ch) {
#pragma unroll
  for (int r = 0; r < 4; r++) {
    xw[(cl * 4 + r) * 36 + ch] = fmaxf(da[r] + ba, 0.f);
    xw[(cl * 4 + r) * 36 + ch + 16] = fmaxf(db[r] + bb, 0.f);
  }
}

__device__ inline ABfrag xpose_read(const float* __restrict__ xw, int lane) {
  const float4* p = (const float4*)(xw + (lane & 15) * 36 + (lane >> 4) * 8);
  float4 v0 = p[0], v1 = p[1];
  ABfrag A;
  A.i = make_int4(cvt_pk_bf16(v0.x, v0.y), cvt_pk_bf16(v0.z, v0.w),
                  cvt_pk_bf16(v1.x, v1.y), cvt_pk_bf16(v1.z, v1.w));
  return A;
}

// gather bundle for one 16-edge tile (R2 + P3 rows)
struct G8 { float2 r0[4], r1[4]; float p30[4], p31[4]; };

__device__ inline void gath(G8& g, const float2* __restrict__ R2,
                            const float* __restrict__ P3, int4 sv, int4 dv, int ch) {
  int sa[4] = {sv.x, sv.y, sv.z, sv.w};
  int da[4] = {dv.x, dv.y, dv.z, dv.w};
#pragma unroll
  for (int r = 0; r < 4; r++) {
    g.r0[r] = R2[(size_t)sa[r] * 32 + ch];
    g.r1[r] = R2[(size_t)sa[r] * 32 + ch + 16];
    g.p30[r] = P3[(size_t)da[r] * 32 + ch];
    g.p31[r] = P3[(size_t)da[r] * 32 + ch + 16];
  }
}

struct GQ { float q0[4], q1[4]; };

__device__ inline void gathq(GQ& g, const float* __restrict__ Q0, int4 sv, int ch) {
  int sa[4] = {sv.x, sv.y, sv.z, sv.w};
#pragma unroll
  for (int r = 0; r < 4; r++) {
    g.q0[r] = Q0[(size_t)sa[r] * 32 + ch];
    g.q1[r] = Q0[(size_t)sa[r] * 32 + ch + 16];
  }
}

struct GA { float a0, a1, a2; };

__device__ inline void gatha(GA& g, const float* __restrict__ ea, int e) {
  g.a0 = ea[(size_t)e * 3 + 0];
  g.a1 = ea[(size_t)e * 3 + 1];
  g.a2 = ea[(size_t)e * 3 + 2];
}

// ==== MFMA fused: edge encoder + first message + scatter (pipelined) ====

__global__ __launch_bounds__(256) void k_fe0_m(
    const float* __restrict__ edge_attr, const int* __restrict__ eidx,
    const float* __restrict__ Q0,
    const int* __restrict__ src_p, const int* __restrict__ dst_p,
    float* __restrict__ acc,
    const float* __restrict__ ws, const float* __restrict__ bs,
    const float* __restrict__ wh, const float* __restrict__ bh,
    const float* __restrict__ we, const float* __restrict__ be,
    const float* __restrict__ Wn,  // w_node_s rows 32..63
    unsigned short* __restrict__ h_edge) {
  __shared__ float xp[4][2][16 * 36];
  int lane = threadIdx.x & 63, wid = threadIdx.x >> 6;
  int cl = lane >> 4, ch = lane & 15;
  float wsv0[8], wsv1[8], wsv2[8], bsv[8];
#pragma unroll
  for (int kk = 0; kk < 8; kk++) {
    int c = cl * 8 + kk;
    wsv0[kk] = ws[c]; wsv1[kk] = ws[32 + c]; wsv2[kk] = ws[64 + c];
    bsv[kk] = bs[c];
  }
  ABfrag wha, whb, wea, web, w2ah, w2al, w2bh, w2bl;
#pragma unroll
  for (int kk = 0; kk < 8; kk++) {
    int k = cl * 8 + kk;
    wha.s[kk] = (short)f2b(wh[k * 32 + ch]);
    whb.s[kk] = (short)f2b(wh[k * 32 + ch + 16]);
    wea.s[kk] = (short)f2b(we[k * 32 + ch]);
    web.s[kk] = (short)f2b(we[k * 32 + ch + 16]);
    unsigned short hi_, lo_;
    splitw(Wn[(32 + k) * 32 + ch], hi_, lo_);      w2ah.s[kk] = (short)hi_; w2al.s[kk] = (short)lo_;
    splitw(Wn[(32 + k) * 32 + ch + 16], hi_, lo_); w2bh.s[kk] = (short)hi_; w2bl.s[kk] = (short)lo_;
  }
  float bha = bh[ch], bhb = bh[ch + 16], bea = be[ch], beb = be[ch + 16];
  int p0 = (blockIdx.x * 4 + wid) * 64;
  f32x4 z = {0.f, 0.f, 0.f, 0.f};
  // upfront index loads for all 4 tiles
  int e0 = eidx[p0 + 0 * 16 + ch], e1 = eidx[p0 + 1 * 16 + ch];
  int e2 = eidx[p0 + 2 * 16 + ch], e3 = eidx[p0 + 3 * 16 + ch];
  int4 sv0 = *(const int4*)(src_p + p0 + 0 * 16 + cl * 4);
  int4 sv1 = *(const int4*)(src_p + p0 + 1 * 16 + cl * 4);
  int4 sv2 = *(const int4*)(src_p + p0 + 2 * 16 + cl * 4);
  int4 sv3 = *(const int4*)(src_p + p0 + 3 * 16 + cl * 4);
  int4 dv0 = *(const int4*)(dst_p + p0 + 0 * 16 + cl * 4);
  int4 dv1 = *(const int4*)(dst_p + p0 + 1 * 16 + cl * 4);
  int4 dv2 = *(const int4*)(dst_p + p0 + 2 * 16 + cl * 4);
  int4 dv3 = *(const int4*)(dst_p + p0 + 3 * 16 + cl * 4);
  GA gaA, gaB;
  GQ gqA, gqB;
  gatha(gaA, edge_attr, e0); gathq(gqA, Q0, sv0, ch);
  gatha(gaB, edge_attr, e1); gathq(gqB, Q0, sv1, ch);

#define FE0_TILE(T, GA_, GQ_, DV_, PP)                                          \
  do {                                                                          \
    int pb = p0 + T * 16;                                                       \
    float* xw = xp[wid][PP];                                                    \
    float h1[8];                                                                \
    _Pragma("unroll") for (int kk = 0; kk < 8; kk++)                            \
        h1[kk] = fmaxf(fmaf(GA_.a0, wsv0[kk],                                   \
                  fmaf(GA_.a1, wsv1[kk], fmaf(GA_.a2, wsv2[kk], bsv[kk]))), 0.f);\
    ABfrag A;                                                                   \
    A.i = make_int4(cvt_pk_bf16(h1[0], h1[1]), cvt_pk_bf16(h1[2], h1[3]),       \
                    cvt_pk_bf16(h1[4], h1[5]), cvt_pk_bf16(h1[6], h1[7]));      \
    f32x4 da = __builtin_amdgcn_mfma_f32_16x16x32_bf16(A.s, wha.s, z, 0, 0, 0); \
    f32x4 db = __builtin_amdgcn_mfma_f32_16x16x32_bf16(A.s, whb.s, z, 0, 0, 0); \
    ep_xpose_write(xw, da, db, bha, bhb, cl, ch);                               \
    A = xpose_read(xw, lane);                                                   \
    da = __builtin_amdgcn_mfma_f32_16x16x32_bf16(A.s, wha.s, z, 0, 0, 0);       \
    db = __builtin_amdgcn_mfma_f32_16x16x32_bf16(A.s, whb.s, z, 0, 0, 0);       \
    ep_xpose_write(xw, da, db, bha, bhb, cl, ch);                               \
    A = xpose_read(xw, lane);                                                   \
    da = __builtin_amdgcn_mfma_f32_16x16x32_bf16(A.s, wea.s, z, 0, 0, 0);       \
    db = __builtin_amdgcn_mfma_f32_16x16x32_bf16(A.s, web.s, z, 0, 0, 0);       \
    _Pragma("unroll") for (int r = 0; r < 4; r++) {                             \
      float h0 = fmaxf(da[r] + bea, 0.f);                                       \
      float hv = fmaxf(db[r] + beb, 0.f);                                       \
      int p = pb + cl * 4 + r;                                                  \
      h_edge[(size_t)p * 32 + ch] = f2b(h0);                                    \
      h_edge[(size_t)p * 32 + ch + 16] = f2b(hv);                               \
      xw[(cl * 4 + r) * 36 + ch] = h0;                                          \
      xw[(cl * 4 + r) * 36 + ch + 16] = hv;                                     \
    }                                                                           \
    A = xpose_read(xw, lane);                                                   \
    f32x4 ma = __builtin_amdgcn_mfma_f32_16x16x32_bf16(A.s, w2al.s, z, 0, 0, 0);\
    ma = __builtin_amdgcn_mfma_f32_16x16x32_bf16(A.s, w2ah.s, ma, 0, 0, 0);     \
    f32x4 mb = __builtin_amdgcn_mfma_f32_16x16x32_bf16(A.s, w2bl.s, z, 0, 0, 0);\
    mb = __builtin_amdgcn_mfma_f32_16x16x32_bf16(A.s, w2bh.s, mb, 0, 0, 0);     \
    int dda[4] = {DV_.x, DV_.y, DV_.z, DV_.w};                                  \
    float va = 0.f, vb = 0.f;                                                   \
    int cur = dda[0];                                                           \
    _Pragma("unroll") for (int r = 0; r < 4; r++) {                             \
      float xa = fmaxf(ma[r] + GQ_.q0[r], 0.f);                                 \
      float xb = fmaxf(mb[r] + GQ_.q1[r], 0.f);                                 \
      if (dda[r] != cur) {                                                      \
        atomicAdd(&acc[(size_t)cur * 32 + ch], va);                             \
        atomicAdd(&acc[(size_t)cur * 32 + ch + 16], vb);                        \
        va = 0.f; vb = 0.f; cur = dda[r];                                       \
      }                                                                         \
      va += xa; vb += xb;                                                       \
    }                                                                           \
    atomicAdd(&acc[(size_t)cur * 32 + ch], va);                                 \
    atomicAdd(&acc[(size_t)cur * 32 + ch + 16], vb);                            \
  } while (0)

  FE0_TILE(0, gaA, gqA, dv0, 0);
  gatha(gaA, edge_attr, e2); gathq(gqA, Q0, sv2, ch);
  FE0_TILE(1, gaB, gqB, dv1, 1);
  gatha(gaB, edge_attr, e3); gathq(gqB, Q0, sv3, ch);
  FE0_TILE(2, gaA, gqA, dv2, 0);
  FE0_TILE(3, gaB, gqB, dv3, 1);
#undef FE0_TILE
}

// ==== MFMA fused: edge update + message + scatter (pipelined) ====
// LAST=1: also c = h_new @ We3 (32->3, split) -> partial; skip h_edge store.

template <int LAST>
__global__ __launch_bounds__(256) void k_fe_t(
    unsigned short* __restrict__ h_edge, const float2* __restrict__ R2,
    const float* __restrict__ P3, const int* __restrict__ src_p,
    const int* __restrict__ dst_p, float* __restrict__ acc,
    const float* __restrict__ We, const float* __restrict__ be,
    const float* __restrict__ Wn, const float* __restrict__ We3,
    float* __restrict__ partial) {
  __shared__ float xp[4][2][16 * 36];
  int lane = threadIdx.x & 63, wid = threadIdx.x >> 6;
  int cl = lane >> 4, ch = lane & 15;
  ABfrag b1ah, b1al, b1bh, b1bl, b2ah, b2al, b2bh, b2bl, w3h, w3l;
#pragma unroll
  for (int kk = 0; kk < 8; kk++) {
    int k = cl * 8 + kk;
    unsigned short hi_, lo_;
    splitw(We[k * 32 + ch], hi_, lo_);             b1ah.s[kk] = (short)hi_; b1al.s[kk] = (short)lo_;
    splitw(We[k * 32 + ch + 16], hi_, lo_);        b1bh.s[kk] = (short)hi_; b1bl.s[kk] = (short)lo_;
    splitw(Wn[(32 + k) * 32 + ch], hi_, lo_);      b2ah.s[kk] = (short)hi_; b2al.s[kk] = (short)lo_;
    splitw(Wn[(32 + k) * 32 + ch + 16], hi_, lo_); b2bh.s[kk] = (short)hi_; b2bl.s[kk] = (short)lo_;
    if (LAST) {
      float v = (ch < 3) ? We3[k * 3 + ch] : 0.f;
      splitw(v, hi_, lo_); w3h.s[kk] = (short)hi_; w3l.s[kk] = (short)lo_;
    }
  }
  float bea = be[ch], beb = be[ch + 16];
  int p0 = (blockIdx.x * 4 + wid) * 64;
  f32x4 z = {0.f, 0.f, 0.f, 0.f};
  ABfrag Af0, Af1, Af2, Af3;
  Af0.i = *(const int4*)(h_edge + (size_t)(p0 + 0 * 16 + ch) * 32 + cl * 8);
  Af1.i = *(const int4*)(h_edge + (size_t)(p0 + 1 * 16 + ch) * 32 + cl * 8);
  Af2.i = *(const int4*)(h_edge + (size_t)(p0 + 2 * 16 + ch) * 32 + cl * 8);
  Af3.i = *(const int4*)(h_edge + (size_t)(p0 + 3 * 16 + ch) * 32 + cl * 8);
  int4 sv0 = *(const int4*)(src_p + p0 + 0 * 16 + cl * 4);
  int4 sv1 = *(const int4*)(src_p + p0 + 1 * 16 + cl * 4);
  int4 sv2 = *(const int4*)(src_p + p0 + 2 * 16 + cl * 4);
  int4 sv3 = *(const int4*)(src_p + p0 + 3 * 16 + cl * 4);
  int4 dv0 = *(const int4*)(dst_p + p0 + 0 * 16 + cl * 4);
  int4 dv1 = *(const int4*)(dst_p + p0 + 1 * 16 + cl * 4);
  int4 dv2 = *(const int4*)(dst_p + p0 + 2 * 16 + cl * 4);
  int4 dv3 = *(const int4*)(dst_p + p0 + 3 * 16 + cl * 4);
  G8 g0, g1;
  gath(g0, R2, P3, sv0, dv0, ch);
  gath(g1, R2, P3, sv1, dv1, ch);

#define FE_TILE(T, GG, DV_, PP)                                                 \
  do {                                                                          \
    int pb = p0 + T * 16;                                                       \
    float* xw = xp[wid][PP];                                                    \
    f32x4 da = __builtin_amdgcn_mfma_f32_16x16x32_bf16(Af##T.s, b1al.s, z, 0, 0, 0); \
    da = __builtin_amdgcn_mfma_f32_16x16x32_bf16(Af##T.s, b1ah.s, da, 0, 0, 0); \
    f32x4 db = __builtin_amdgcn_mfma_f32_16x16x32_bf16(Af##T.s, b1bl.s, z, 0, 0, 0); \
    db = __builtin_amdgcn_mfma_f32_16x16x32_bf16(Af##T.s, b1bh.s, db, 0, 0, 0); \
    _Pragma("unroll") for (int r = 0; r < 4; r++) {                             \
      float h0 = fmaxf(da[r] + GG.r0[r].x + GG.p30[r] + bea, 0.f);              \
      float hv = fmaxf(db[r] + GG.r1[r].x + GG.p31[r] + beb, 0.f);              \
      int p = pb + cl * 4 + r;                                                  \
      if (!LAST) {                                                              \
        h_edge[(size_t)p * 32 + ch] = f2b(h0);                                  \
        h_edge[(size_t)p * 32 + ch + 16] = f2b(hv);                             \
      }                                                                         \
      xw[(cl * 4 + r) * 36 + ch] = h0;                                          \
      xw[(cl * 4 + r) * 36 + ch + 16] = hv;                                     \
    }                                                                           \
    ABfrag A2 = xpose_read(xw, lane);                                           \
    f32x4 ma = __builtin_amdgcn_mfma_f32_16x16x32_bf16(A2.s, b2al.s, z, 0, 0, 0); \
    ma = __builtin_amdgcn_mfma_f32_16x16x32_bf16(A2.s, b2ah.s, ma, 0, 0, 0);    \
    f32x4 mb = __builtin_amdgcn_mfma_f32_16x16x32_bf16(A2.s, b2bl.s, z, 0, 0, 0); \
    mb = __builtin_amdgcn_mfma_f32_16x16x32_bf16(A2.s, b2bh.s, mb, 0, 0, 0);    \
    if (LAST) {                                                                 \
      f32x4 dc = __builtin_amdgcn_mfma_f32_16x16x32_bf16(A2.s, w3l.s, z, 0, 0, 0); \
      dc = __builtin_amdgcn_mfma_f32_16x16x32_bf16(A2.s, w3h.s, dc, 0, 0, 0);   \
      if (ch < 3) {                                                             \
        _Pragma("unroll") for (int r = 0; r < 4; r++)                           \
            partial[(size_t)(pb + cl * 4 + r) * 3 + ch] = dc[r];                \
      }                                                                         \
    }                                                                           \
    int dda[4] = {DV_.x, DV_.y, DV_.z, DV_.w};                                  \
    float va = 0.f, vb = 0.f;                                                   \
    int cur = dda[0];                                                           \
    _Pragma("unroll") for (int r = 0; r < 4; r++) {                             \
      float xa = fmaxf(ma[r] + GG.r0[r].y, 0.f);                                \
      float xb = fmaxf(mb[r] + GG.r1[r].y, 0.f);                                \
      if (dda[r] != cur) {                                                      \
        atomicAdd(&acc[(size_t)cur * 32 + ch], va);                             \
        atomicAdd(&acc[(size_t)cur * 32 + ch + 16], vb);                        \
        va = 0.f; vb = 0.f; cur = dda[r];                                       \
      }                                                                         \
      va += xa; vb += xb;                                                       \
    }                                                                           \
    atomicAdd(&acc[(size_t)cur * 32 + ch], va);                                 \
    atomicAdd(&acc[(size_t)cur * 32 + ch + 16], vb);                            \
  } while (0)

  FE_TILE(0, g0, dv0, 0);
  gath(g0, R2, P3, sv2, dv2, ch);
  FE_TILE(1, g1, dv1, 1);
  gath(g1, R2, P3, sv3, dv3, ch);
  FE_TILE(2, g0, dv2, 0);
  FE_TILE(3, g1, dv3, 1);
#undef FE_TILE
}

// ==== final: out[e] = ea[e] + partial[inv[e]] + P2f[src[e]] + P3f[dst[e]] + b ====

__global__ __launch_bounds__(256) void k_fe4e(
    const float* __restrict__ partial, const int* __restrict__ inv_p,
    const float* __restrict__ edge_attr, const int* __restrict__ src,
    const int* __restrict__ dstv, const float* __restrict__ P2f,
    const float* __restrict__ P3f, const float* __restrict__ be,
    float* __restrict__ out) {
  int e = blockIdx.x * blockDim.x + threadIdx.x;
  if (e >= NE) return;
  int p = inv_p[e];
  int s = src[e], d = dstv[e];
  float c0 = partial[(size_t)p * 3 + 0];
  float c1 = partial[(size_t)p * 3 + 1];
  float c2 = partial[(size_t)p * 3 + 2];
  out[(size_t)e * 3 + 0] = edge_attr[(size_t)e * 3 + 0] + c0 + P2f[(size_t)s * 3 + 0] + P3f[(size_t)d * 3 + 0] + be[0];
  out[(size_t)e * 3 + 1] = edge_attr[(size_t)e * 3 + 1] + c1 + P2f[(size_t)s * 3 + 1] + P3f[(size_t)d * 3 + 1] + be[1];
  out[(size_t)e * 3 + 2] = edge_attr[(size_t)e * 3 + 2] + c2 + P2f[(size_t)s * 3 + 2] + P3f[(size_t)d * 3 + 2] + be[2];
}

// ============================ launch ============================

extern "C" void kernel_launch(void* const* d_in, const int* in_sizes, int n_in,
                              void* d_out, int out_size, void* d_ws, size_t ws_size,
                              hipStream_t stream) {
  const float* x = (const float*)d_in[0];
  const float* edge_attr = (const float*)d_in[1];
  const int* ei = (const int*)d_in[2];
  const int* src = ei;
  const int* dst = ei + NE;
  const float* w_enc_node_s = (const float*)d_in[3];
  const float* b_enc_node_s = (const float*)d_in[4];
  const float* w_enc_node_h = (const float*)d_in[5];
  const float* b_enc_node_h = (const float*)d_in[6];
  const float* w_enc_node_e = (const float*)d_in[7];
  const float* b_enc_node_e = (const float*)d_in[8];
  const float* w_enc_edge_s = (const float*)d_in[9];
  const float* b_enc_edge_s = (const float*)d_in[10];
  const float* w_enc_edge_h = (const float*)d_in[11];
  const float* b_enc_edge_h = (const float*)d_in[12];
  const float* w_enc_edge_e = (const float*)d_in[13];
  const float* b_enc_edge_e = (const float*)d_in[14];
  const float* w_node_s = (const float*)d_in[15];
  const float* w_node_h = (const float*)d_in[16];
  const float* w_node_e = (const float*)d_in[17];
  const float* w_edge_s = (const float*)d_in[18];
  const float* b_edge_s = (const float*)d_in[19];
  const float* w_edge_h = (const float*)d_in[20];
  const float* b_edge_h = (const float*)d_in[21];
  const float* w_edge_e = (const float*)d_in[22];
  const float* b_edge_e = (const float*)d_in[23];

  // workspace layout (~213 MB; 238 MB proven safe in round 1)
  char* w = (char*)d_ws;
  unsigned short* h_edge = (unsigned short*)w; w += (size_t)NE * D * 2;  // 102.4 MB
  int* eidx = (int*)w;        w += (size_t)NE * 4;            // 6.4
  int* inv_p = (int*)w;       w += (size_t)NE * 4;            // 6.4
  int* src_p = (int*)w;       w += (size_t)NE * 4;            // 6.4
  int* dst_p = (int*)w;       w += (size_t)NE * 4;            // 6.4
  float* partialE = (float*)w; w += (size_t)NE * 3 * 4;       // 19.2
  float* acc = (float*)w;     w += (size_t)NN * D * 4;        // 12.8
  float2* R2 = (float2*)w;    w += (size_t)NN * D * 8;        // 25.6
  float* P3 = (float*)w;      w += (size_t)NN * D * 4;        // 12.8
  float* Q0 = (float*)w;      w += (size_t)NN * D * 4;        // 12.8
  float* P2f = P3;
  float* P3f = P3 + (size_t)NN * 3;
  int* cnt = (int*)w;         w += (size_t)NN * 4;
  float* inv_deg = (float*)w; w += (size_t)NN * 4;
  int* rowptr = (int*)w;      w += (size_t)(NN + 1) * 4;
  int* fill = (int*)w;        w += (size_t)NN * 4;
  int* partial = (int*)w;     w += 4096;

  hipMemsetAsync(cnt, 0, (size_t)NN * 4, stream);
  hipMemsetAsync(fill, 0, (size_t)NN * 4, stream);
  hipMemsetAsync(acc, 0, (size_t)NN * D * 4, stream);

  k_deg<<<1024, 256, 0, stream>>>(dst, cnt);
  k_invdeg<<<(NN + 255) / 256, 256, 0, stream>>>(cnt, inv_deg);
  int nb = (NN + 1023) / 1024;  // 98
  k_scanA<<<nb, 1024, 0, stream>>>(cnt, rowptr, partial);
  k_scanB<<<1, 128, 0, stream>>>(partial, nb);
  k_scanC<<<nb, 1024, 0, stream>>>(rowptr, partial);
  k_fill<<<1024, 256, 0, stream>>>(src, dst, rowptr, fill, eidx, src_p, dst_p, inv_p);

  k_node_enc_fin<<<1024, 256, 0, stream>>>(x, w_enc_node_s, b_enc_node_s,
                                           w_enc_node_h, b_enc_node_h,
                                           w_enc_node_e, b_enc_node_e,
                                           w_node_s, Q0);

  int feb = NE / 256;  // 6250 blocks: 4 waves x 64 edges

  k_fe0_m<<<feb, 256, 0, stream>>>(edge_attr, eidx, Q0, src_p, dst_p, acc,
                                   w_enc_edge_s, b_enc_edge_s,
                                   w_enc_edge_h, b_enc_edge_h,
                                   w_enc_edge_e, b_enc_edge_e,
                                   w_node_s, h_edge);
  k_fin<<<1024, 256, 0, stream>>>(acc, inv_deg, w_edge_s, w_node_h, R2, P3);
  k_fe_t<0><<<feb, 256, 0, stream>>>(h_edge, R2, P3, src_p, dst_p, acc,
                                     w_edge_s, b_edge_s, w_node_h, nullptr, nullptr);
  k_fin<<<1024, 256, 0, stream>>>(acc, inv_deg, w_edge_h, w_node_h, R2, P3);
  k_fe_t<0><<<feb, 256, 0, stream>>>(h_edge, R2, P3, src_p, dst_p, acc,
                                     w_edge_h, b_edge_h, w_node_h, nullptr, nullptr);
  k_fin<<<1024, 256, 0, stream>>>(acc, inv_deg, w_edge_h, w_node_e, R2, P3);
  k_fe_t<1><<<feb, 256, 0, stream>>>(h_edge, R2, P3, src_p, dst_p, acc,
                                     w_edge_h, b_edge_h, w_node_e, w_edge_e, partialE);
  k_fin4<<<1024, 256, 0, stream>>>(acc, inv_deg, w_edge_e, P2f, P3f);
  k_fe4e<<<(NE + 255) / 256, 256, 0, stream>>>(partialE, inv_p, edge_attr, src, dst,
                                               P2f, P3f, b_edge_e, (float*)d_out);
}